// Round 2
// baseline (64.594 us; speedup 1.0000x reference)
//
#include <hip/hip_runtime.h>
#include <math.h>

#define NB 4
#define WDIM 128
#define KDIM 256
#define EDIM 256
#define TK 4

// ---------------- Kernel A (unchanged from round 1) ----------------
// u[b,k,e] = sum_w v[b,k,w]*W1[e,w];  t[b,k,e] = sum_w v[b,k,w]*W2[e,w] + lin_b[e]
__global__ __launch_bounds__(256) void k_ut(const float* __restrict__ x,
                                            const float* __restrict__ lin_w,
                                            const float* __restrict__ lin_b,
                                            float* __restrict__ u_ws,
                                            float* __restrict__ t_ws) {
    __shared__ float vrow[TK][WDIM];
    const int blk = blockIdx.x;
    const int b  = blk / (KDIM / TK);
    const int k0 = (blk % (KDIM / TK)) * TK;
    const int tid = threadIdx.x;

    if (tid < WDIM) {
        float4 vv = *(const float4*)(x + (size_t)b * WDIM * KDIM + (size_t)tid * KDIM + k0);
        vrow[0][tid] = vv.x; vrow[1][tid] = vv.y; vrow[2][tid] = vv.z; vrow[3][tid] = vv.w;
    }
    __syncthreads();

    const int e = tid;
    const float4* wrow = (const float4*)(lin_w + (size_t)e * 2 * WDIM);
    float accu[TK], acct[TK];
#pragma unroll
    for (int kk = 0; kk < TK; ++kk) { accu[kk] = 0.f; acct[kk] = 0.f; }

    for (int w4 = 0; w4 < WDIM / 4; ++w4) {
        float4 w1 = wrow[w4];
        float4 w2 = wrow[WDIM / 4 + w4];
#pragma unroll
        for (int kk = 0; kk < TK; ++kk) {
            float v0 = vrow[kk][w4 * 4 + 0];
            float v1 = vrow[kk][w4 * 4 + 1];
            float v2 = vrow[kk][w4 * 4 + 2];
            float v3 = vrow[kk][w4 * 4 + 3];
            accu[kk] += w1.x * v0 + w1.y * v1 + w1.z * v2 + w1.w * v3;
            acct[kk] += w2.x * v0 + w2.y * v1 + w2.z * v2 + w2.w * v3;
        }
    }
    const float lb = lin_b[e];
#pragma unroll
    for (int kk = 0; kk < TK; ++kk) {
        size_t off = ((size_t)b * KDIM + (k0 + kk)) * EDIM + e;
        u_ws[off] = accu[kk];
        t_ws[off] = acct[kk] + lb;
    }
}

// ---------------- Kernel B (rewritten) ----------------
// Block = (b, i-tile of 4). 256 threads = 4 waves.
// wave wv = e-quarter; lane = (jj = lane&31, eh = lane>>5); lane's e-slice = wv*64+eh*32 .. +32.
// e_ij = sum_partials(0.4a*|u+t|) + ru[i] + rt[j] + bias, then softmax, then h = sigmoid(attn @ v).
__global__ __launch_bounds__(256, 1) void k_attn2(const float* __restrict__ x,
                                                  const float* __restrict__ a_vec,
                                                  const float* __restrict__ bias,
                                                  const float* __restrict__ u_ws,
                                                  const float* __restrict__ t_ws,
                                                  float* __restrict__ out) {
    __shared__ float tbuf[32 * 260];   // t chunk [32 j][260]; reused as x chunk [128][36] in h-phase
    __shared__ float e_red[8 * 32 * 4]; // partial e sums: [slice 8][j 32][i 4]
    __shared__ float rt_red[8 * 32];    // partial rt sums: [slice 8][j 32]
    __shared__ float e_lds[4 * 260];    // e rows / attn rows, padded stride 260
    __shared__ float ru_red[16];
    __shared__ float ru_lds[4];

    const int b  = blockIdx.x >> 6;
    const int i0 = (blockIdx.x & 63) << 2;
    const int tid  = threadIdx.x;
    const int lane = tid & 63;
    const int wv   = tid >> 6;
    const int jj   = lane & 31;
    const int eh   = lane >> 5;
    const int e_base = wv * 64 + eh * 32;
    const int slice  = tid >> 5;        // == wv*2 + eh

    // ---- prologue: a2 (=0.4*a) and u slices into registers ----
    float4 a2r[8];
    {
        const float4* ap = (const float4*)(a_vec + e_base);
#pragma unroll
        for (int q = 0; q < 8; ++q) {
            float4 v = ap[q];
            a2r[q] = make_float4(0.4f * v.x, 0.4f * v.y, 0.4f * v.z, 0.4f * v.w);
        }
    }
    float4 ur[4][8];
#pragma unroll
    for (int i = 0; i < 4; ++i) {
        const float4* up = (const float4*)(u_ws + ((size_t)b * KDIM + i0 + i) * EDIM + e_base);
#pragma unroll
        for (int q = 0; q < 8; ++q) ur[i][q] = up[q];
    }
    // ru partial: ru[i] = 1.5 * sum_e a2[e]*u[i][e]  (1.5*0.4 = 0.6)
    {
        float pr[4];
#pragma unroll
        for (int i = 0; i < 4; ++i) {
            float s = 0.f;
#pragma unroll
            for (int q = 0; q < 8; ++q) {
                s += a2r[q].x * ur[i][q].x + a2r[q].y * ur[i][q].y
                   + a2r[q].z * ur[i][q].z + a2r[q].w * ur[i][q].w;
            }
            pr[i] = s;
        }
#pragma unroll
        for (int i = 0; i < 4; ++i) pr[i] += __shfl_xor(pr[i], 32, 64);
        if (lane == 0) {
#pragma unroll
            for (int i = 0; i < 4; ++i) ru_red[wv * 4 + i] = pr[i];
        }
    }
    __syncthreads();
    if (tid < 4) ru_lds[tid] = 1.5f * (ru_red[tid] + ru_red[4 + tid] + ru_red[8 + tid] + ru_red[12 + tid]);

    // ---- e-phase: 8 chunks of 32 j rows ----
    const float4* tp = (const float4*)(t_ws + (size_t)b * KDIM * EDIM);
    float4 st[8];
#pragma unroll
    for (int r = 0; r < 8; ++r) {                 // preload chunk 0
        int f = r * 256 + tid;                    // float4 index in [32][64]
        st[r] = tp[(size_t)(f >> 6) * 64 + (f & 63)];
    }

    for (int c = 0; c < 8; ++c) {
        const int j0 = c * 32;
        __syncthreads();                          // prev finalize done; tbuf free
#pragma unroll
        for (int r = 0; r < 8; ++r) {             // reg -> LDS (padded, conflict-free)
            int f = r * 256 + tid;
            *(float4*)&tbuf[(f >> 6) * 260 + (f & 63) * 4] = st[r];
        }
        __syncthreads();
        if (c < 7) {                              // issue next chunk's global loads early
#pragma unroll
            for (int r = 0; r < 8; ++r) {
                int f = r * 256 + tid;
                st[r] = tp[(size_t)(j0 + 32 + (f >> 6)) * 64 + (f & 63)];
            }
        }
        // compute partial |u+t| dot a2 for 4 i's + rt partial
        float acc[4] = {0.f, 0.f, 0.f, 0.f};
        float prt = 0.f;
#pragma unroll
        for (int q = 0; q < 8; ++q) {
            float4 t4 = *(const float4*)&tbuf[jj * 260 + e_base + q * 4];
            prt += a2r[q].x * t4.x + a2r[q].y * t4.y + a2r[q].z * t4.z + a2r[q].w * t4.w;
#pragma unroll
            for (int i = 0; i < 4; ++i) {
                float px = ur[i][q].x + t4.x;
                float py = ur[i][q].y + t4.y;
                float pz = ur[i][q].z + t4.z;
                float pw = ur[i][q].w + t4.w;
                acc[i] += a2r[q].x * fabsf(px) + a2r[q].y * fabsf(py)
                        + a2r[q].z * fabsf(pz) + a2r[q].w * fabsf(pw);
            }
        }
        *(float4*)&e_red[(slice * 32 + jj) * 4] = make_float4(acc[0], acc[1], acc[2], acc[3]);
        rt_red[slice * 32 + jj] = prt;
        __syncthreads();
        if (tid < 128) {                          // finalize e_ij for this chunk
            const int i  = tid & 3;
            const int jl = tid >> 2;
            float s = 0.f;
#pragma unroll
            for (int q = 0; q < 8; ++q) s += e_red[q * 128 + tid];
            float rt = 0.f;
#pragma unroll
            for (int q = 0; q < 8; ++q) rt += rt_red[q * 32 + jl];
            float eij = s + ru_lds[i] + 1.5f * rt + bias[(size_t)(i0 + i) * KDIM + j0 + jl];
            e_lds[i * 260 + j0 + jl] = eij;
        }
    }
    __syncthreads();

    // ---- preload x chunk 0 (hide latency under softmax) ----
    const float* xb = x + (size_t)b * WDIM * KDIM;
    float4 xst[4];
#pragma unroll
    for (int r = 0; r < 4; ++r) {
        int f = r * 256 + tid;                    // float4 idx in [128][8]
        xst[r] = *(const float4*)(xb + (size_t)(f >> 3) * KDIM + (f & 7) * 4);
    }

    // ---- softmax: wave wv handles row i=wv ----
    {
        const int i = wv;
        float4 ev = *(const float4*)&e_lds[i * 260 + lane * 4];
        float m = fmaxf(fmaxf(ev.x, ev.y), fmaxf(ev.z, ev.w));
#pragma unroll
        for (int o = 32; o > 0; o >>= 1) m = fmaxf(m, __shfl_xor(m, o, 64));
        float4 p;
        p.x = expf(ev.x - m); p.y = expf(ev.y - m);
        p.z = expf(ev.z - m); p.w = expf(ev.w - m);
        float s = p.x + p.y + p.z + p.w;
#pragma unroll
        for (int o = 32; o > 0; o >>= 1) s += __shfl_xor(s, o, 64);
        float inv = 1.0f / s;
        p.x *= inv; p.y *= inv; p.z *= inv; p.w *= inv;
        *(float4*)&e_lds[i * 260 + lane * 4] = p;
    }
    __syncthreads();

    // ---- h-phase: 8 chunks of 32 j columns of x; thread = (w, i-pair) ----
    const int w  = tid & 127;
    const int ih = tid >> 7;
    float hacc0 = 0.f, hacc1 = 0.f;

    for (int c = 0; c < 8; ++c) {
        const int j0 = c * 32;
        __syncthreads();
#pragma unroll
        for (int r = 0; r < 4; ++r) {             // reg -> LDS [128][36]
            int f = r * 256 + tid;
            *(float4*)&tbuf[(f >> 3) * 36 + (f & 7) * 4] = xst[r];
        }
        __syncthreads();
        if (c < 7) {
#pragma unroll
            for (int r = 0; r < 4; ++r) {
                int f = r * 256 + tid;
                xst[r] = *(const float4*)(xb + (size_t)(f >> 3) * KDIM + (j0 + 32) + (f & 7) * 4);
            }
        }
#pragma unroll
        for (int q = 0; q < 8; ++q) {
            float4 x4 = *(const float4*)&tbuf[w * 36 + q * 4];
            float4 a0 = *(const float4*)&e_lds[(ih * 2 + 0) * 260 + j0 + q * 4];
            float4 a1 = *(const float4*)&e_lds[(ih * 2 + 1) * 260 + j0 + q * 4];
            hacc0 += a0.x * x4.x + a0.y * x4.y + a0.z * x4.z + a0.w * x4.w;
            hacc1 += a1.x * x4.x + a1.y * x4.y + a1.z * x4.z + a1.w * x4.w;
        }
    }

    float2 o;
    o.x = 1.f / (1.f + expf(-hacc0));
    o.y = 1.f / (1.f + expf(-hacc1));
    *(float2*)(out + (size_t)b * WDIM * KDIM + (size_t)w * KDIM + i0 + ih * 2) = o;
}

extern "C" void kernel_launch(void* const* d_in, const int* in_sizes, int n_in,
                              void* d_out, int out_size, void* d_ws, size_t ws_size,
                              hipStream_t stream) {
    const float* x     = (const float*)d_in[0];
    const float* lin_w = (const float*)d_in[1];
    const float* lin_b = (const float*)d_in[2];
    const float* a_vec = (const float*)d_in[3];
    const float* bias  = (const float*)d_in[4];
    float* out = (float*)d_out;

    float* u_ws = (float*)d_ws;
    float* t_ws = u_ws + (size_t)NB * KDIM * EDIM;

    k_ut<<<NB * (KDIM / TK), 256, 0, stream>>>(x, lin_w, lin_b, u_ws, t_ws);
    k_attn2<<<NB * 64, 256, 0, stream>>>(x, a_vec, bias, u_ws, t_ws, out);
}

// Round 3
// 53.821 us; speedup vs baseline: 1.2002x; 1.2002x over previous
//
#include <hip/hip_runtime.h>
#include <math.h>

#define NB 4
#define WDIM 128
#define KDIM 256
#define EDIM 256

// ---------------- k_ut: u,t GEMMs + ru/rt row-sums ----------------
// grid: NB*(KDIM/2) = 512 blocks, 256 threads. Block = (b, k0..k0+1). Thread = e.
// u[b,k,e] = sum_w v[k,w]*W1[e,w]; t[b,k,e] = sum_w v[k,w]*W2[e,w] + lin_b[e]
// ru[b,k] = 1.5*sum_e 0.4*a[e]*u[b,k,e]; rt[b,k] = 1.5*sum_e 0.4*a[e]*t[b,k,e]
__global__ __launch_bounds__(256) void k_ut(const float* __restrict__ x,
                                            const float* __restrict__ lin_w,
                                            const float* __restrict__ lin_b,
                                            const float* __restrict__ a_vec,
                                            float* __restrict__ u_ws,
                                            float* __restrict__ t_ws,
                                            float* __restrict__ ru_ws,
                                            float* __restrict__ rt_ws) {
    __shared__ float vrow[2][WDIM];
    __shared__ float red[4][4];
    const int blk = blockIdx.x;
    const int b  = blk >> 7;
    const int k0 = (blk & 127) << 1;
    const int tid = threadIdx.x;

    if (tid < WDIM) {
        const float* xp = x + ((size_t)b * WDIM + tid) * KDIM + k0;
        vrow[0][tid] = xp[0];
        vrow[1][tid] = xp[1];
    }
    __syncthreads();

    const int e = tid;
    const float4* wr = (const float4*)(lin_w + (size_t)e * 2 * WDIM);
    float au0 = 0.f, au1 = 0.f, at0 = 0.f, at1 = 0.f;
#pragma unroll 8
    for (int q = 0; q < WDIM / 4; ++q) {
        float4 w1 = wr[q];
        float4 w2 = wr[WDIM / 4 + q];
        float4 v0 = *(const float4*)&vrow[0][q * 4];
        float4 v1 = *(const float4*)&vrow[1][q * 4];
        au0 += w1.x * v0.x + w1.y * v0.y + w1.z * v0.z + w1.w * v0.w;
        au1 += w1.x * v1.x + w1.y * v1.y + w1.z * v1.z + w1.w * v1.w;
        at0 += w2.x * v0.x + w2.y * v0.y + w2.z * v0.z + w2.w * v0.w;
        at1 += w2.x * v1.x + w2.y * v1.y + w2.z * v1.z + w2.w * v1.w;
    }
    const float lb = lin_b[e];
    at0 += lb; at1 += lb;
    const size_t o0 = ((size_t)b * KDIM + k0) * EDIM + e;
    u_ws[o0] = au0; u_ws[o0 + EDIM] = au1;
    t_ws[o0] = at0; t_ws[o0 + EDIM] = at1;

    // ru/rt partials (butterfly over 64 lanes, then cross-wave via tiny LDS)
    const float a2 = 0.4f * a_vec[e];
    float p0 = a2 * au0, p1 = a2 * au1, p2 = a2 * at0, p3 = a2 * at1;
#pragma unroll
    for (int off = 1; off < 64; off <<= 1) {
        p0 += __shfl_xor(p0, off, 64);
        p1 += __shfl_xor(p1, off, 64);
        p2 += __shfl_xor(p2, off, 64);
        p3 += __shfl_xor(p3, off, 64);
    }
    if ((tid & 63) == 0) {
        const int wv = tid >> 6;
        red[wv][0] = p0; red[wv][1] = p1; red[wv][2] = p2; red[wv][3] = p3;
    }
    __syncthreads();
    if (tid < 4) {
        float v = 1.5f * (red[0][tid] + red[1][tid] + red[2][tid] + red[3][tid]);
        if (tid < 2) ru_ws[b * KDIM + k0 + tid]       = v;
        else         rt_ws[b * KDIM + k0 + (tid - 2)] = v;
    }
}

// ---------------- k_e: e[b,i,j] = sum_e a2|u_i+t_j| + ru_i + rt_j + bias ----------------
// grid: NB*256 = 1024 blocks, 256 threads, NO LDS, NO barriers.
// blk = b*256 + itile*8 + jtile  (itile in [0,32), jtile in [0,8))
// wave wv -> i-pair i0 = itile*8 + wv*2;  j-tile = jtile*32.
// lane = s*8 + jj: s = e-slice (32 e's), jj = j within group of 8.
__global__ __launch_bounds__(256, 3) void k_e(const float* __restrict__ a_vec,
                                              const float* __restrict__ bias,
                                              const float* __restrict__ u_ws,
                                              const float* __restrict__ t_ws,
                                              const float* __restrict__ ru_ws,
                                              const float* __restrict__ rt_ws,
                                              float* __restrict__ e_ws) {
    const int blk   = blockIdx.x;
    const int jtile = blk & 7;
    const int itile = (blk >> 3) & 31;
    const int b     = blk >> 8;
    const int tid  = threadIdx.x;
    const int wv   = tid >> 6;
    const int lane = tid & 63;
    const int s    = lane >> 3;
    const int jj   = lane & 7;
    const int e_base = s * 32;
    const int i0 = itile * 8 + wv * 2;
    const int j0 = jtile * 32;

    const float4* a4 = (const float4*)(a_vec + e_base);
    const float4* u4 = (const float4*)(u_ws + ((size_t)b * KDIM + i0) * EDIM + e_base);
    float4 a2[8], u0[8], u1[8];
#pragma unroll
    for (int q = 0; q < 8; ++q) {
        float4 av = a4[q];
        a2[q] = make_float4(0.4f * av.x, 0.4f * av.y, 0.4f * av.z, 0.4f * av.w);
        u0[q] = u4[q];
        u1[q] = u4[EDIM / 4 + q];
    }
    const float ru0 = ru_ws[b * KDIM + i0];
    const float ru1 = ru_ws[b * KDIM + i0 + 1];
    const float* tb = t_ws + (size_t)b * KDIM * EDIM;

    for (int jg = 0; jg < 4; ++jg) {
        const int j = j0 + jg * 8 + jj;
        const float4* tp = (const float4*)(tb + (size_t)j * EDIM + e_base);
        float acc0 = 0.f, acc1 = 0.f;
#pragma unroll
        for (int q = 0; q < 8; ++q) {
            float4 t4 = tp[q];
            acc0 += a2[q].x * fabsf(u0[q].x + t4.x) + a2[q].y * fabsf(u0[q].y + t4.y)
                  + a2[q].z * fabsf(u0[q].z + t4.z) + a2[q].w * fabsf(u0[q].w + t4.w);
            acc1 += a2[q].x * fabsf(u1[q].x + t4.x) + a2[q].y * fabsf(u1[q].y + t4.y)
                  + a2[q].z * fabsf(u1[q].z + t4.z) + a2[q].w * fabsf(u1[q].w + t4.w);
        }
        // reduce over s (lane bits 3..5)
        acc0 += __shfl_xor(acc0, 8, 64);  acc1 += __shfl_xor(acc1, 8, 64);
        acc0 += __shfl_xor(acc0, 16, 64); acc1 += __shfl_xor(acc1, 16, 64);
        acc0 += __shfl_xor(acc0, 32, 64); acc1 += __shfl_xor(acc1, 32, 64);
        if (lane < 8) {
            const float rt = rt_ws[b * KDIM + j];
            e_ws[((size_t)b * KDIM + i0) * KDIM + j]     = acc0 + ru0 + rt + bias[(i0    ) * KDIM + j];
            e_ws[((size_t)b * KDIM + i0 + 1) * KDIM + j] = acc1 + ru1 + rt + bias[(i0 + 1) * KDIM + j];
        }
    }
}

// ---------------- k_sh: row softmax + h = sigmoid(attn @ v), write transposed ----------------
// grid: NB*(KDIM/2) = 512 blocks, 256 threads. Block = (b, i0..i0+1).
// wave wv: r = wv&1 (which i-row), whalf = wv>>1 (which 64 w's).
__global__ __launch_bounds__(256) void k_sh(const float* __restrict__ x,
                                            const float* __restrict__ e_ws,
                                            float* __restrict__ out) {
    __shared__ float attn_lds[2][EDIM + 4];
    const int blk = blockIdx.x;
    const int b  = blk >> 7;
    const int i0 = (blk & 127) << 1;
    const int tid  = threadIdx.x;
    const int wv   = tid >> 6;
    const int lane = tid & 63;
    const int r     = wv & 1;
    const int whalf = wv >> 1;

    // softmax of row i0+r (whalf 0/1 compute redundantly; only whalf 0 stores)
    float4 ev = *(const float4*)(e_ws + ((size_t)b * KDIM + i0 + r) * KDIM + lane * 4);
    float m = fmaxf(fmaxf(ev.x, ev.y), fmaxf(ev.z, ev.w));
#pragma unroll
    for (int off = 1; off < 64; off <<= 1) m = fmaxf(m, __shfl_xor(m, off, 64));
    float4 p;
    p.x = __expf(ev.x - m); p.y = __expf(ev.y - m);
    p.z = __expf(ev.z - m); p.w = __expf(ev.w - m);
    float ssum = p.x + p.y + p.z + p.w;
#pragma unroll
    for (int off = 1; off < 64; off <<= 1) ssum += __shfl_xor(ssum, off, 64);
    const float inv = 1.0f / ssum;
    p.x *= inv; p.y *= inv; p.z *= inv; p.w *= inv;
    if (whalf == 0) *(float4*)&attn_lds[r][lane * 4] = p;
    __syncthreads();

    // h-phase: lane = w16*4 + js; 4 chunks of 16 w's -> 64 w's per wave
    const int js  = lane & 3;
    const int w16 = lane >> 2;
    const float* xb = x + (size_t)b * WDIM * KDIM;
    const float* arow = attn_lds[r];
#pragma unroll
    for (int c = 0; c < 4; ++c) {
        const int w = whalf * 64 + c * 16 + w16;
        const float4* xr = (const float4*)(xb + (size_t)w * KDIM);
        float acc = 0.f;
#pragma unroll
        for (int jl = 0; jl < 16; ++jl) {
            float4 x4 = xr[jl * 4 + js];
            float4 a4 = *(const float4*)&arow[jl * 16 + js * 4];
            acc += a4.x * x4.x + a4.y * x4.y + a4.z * x4.z + a4.w * x4.w;
        }
        acc += __shfl_xor(acc, 1, 64);
        acc += __shfl_xor(acc, 2, 64);
        if (js == 0) {
            out[(size_t)b * WDIM * KDIM + (size_t)w * KDIM + i0 + r] =
                1.f / (1.f + __expf(-acc));
        }
    }
}

extern "C" void kernel_launch(void* const* d_in, const int* in_sizes, int n_in,
                              void* d_out, int out_size, void* d_ws, size_t ws_size,
                              hipStream_t stream) {
    (void)in_sizes; (void)n_in; (void)out_size; (void)ws_size;
    const float* x     = (const float*)d_in[0];
    const float* lin_w = (const float*)d_in[1];
    const float* lin_b = (const float*)d_in[2];
    const float* a_vec = (const float*)d_in[3];
    const float* bias  = (const float*)d_in[4];
    float* out = (float*)d_out;

    float* u_ws  = (float*)d_ws;                       // 262144 f
    float* t_ws  = u_ws + (size_t)NB * KDIM * EDIM;    // 262144 f
    float* e_ws  = t_ws + (size_t)NB * KDIM * EDIM;    // 262144 f
    float* ru_ws = e_ws + (size_t)NB * KDIM * KDIM;    // 1024 f
    float* rt_ws = ru_ws + NB * KDIM;                  // 1024 f

    k_ut<<<NB * (KDIM / 2), 256, 0, stream>>>(x, lin_w, lin_b, a_vec, u_ws, t_ws, ru_ws, rt_ws);
    k_e<<<NB * 256, 256, 0, stream>>>(a_vec, bias, u_ws, t_ws, ru_ws, rt_ws, e_ws);
    k_sh<<<NB * (KDIM / 2), 256, 0, stream>>>(x, e_ws, out);
}

// Round 4
// 35.429 us; speedup vs baseline: 1.8232x; 1.5192x over previous
//
#include <hip/hip_runtime.h>
#include <math.h>

#define NB 4
#define WDIM 128
#define KDIM 256
#define EDIM 256

// ---------------- k_ut3: dual GEMM u,t ----------------
// grid 256: blk = b*64 + kt*4 + eq.  Block covers k0..k0+15, e-quarter (64 e's).
// thread: e = eq*64 + (tid&63), ks = tid>>6 (4 k's each).
__global__ __launch_bounds__(256) void k_ut3(const float* __restrict__ x,
                                             const float* __restrict__ lin_w,
                                             const float* __restrict__ lin_b,
                                             float* __restrict__ u_ws,
                                             float* __restrict__ t_ws) {
    __shared__ float vrow[16 * WDIM];   // [k 16][w 128]
    const int blk = blockIdx.x;
    const int b  = blk >> 6;
    const int kt = (blk >> 2) & 15;
    const int eq = blk & 3;
    const int k0 = kt * 16;
    const int tid = threadIdx.x;
    const int e  = eq * 64 + (tid & 63);
    const int ks = tid >> 6;

    if (tid < WDIM) {
        const float* xp = x + ((size_t)b * WDIM + tid) * KDIM + k0;
#pragma unroll
        for (int q = 0; q < 4; ++q) {
            float4 v = *(const float4*)(xp + q * 4);
            vrow[(q * 4 + 0) * WDIM + tid] = v.x;
            vrow[(q * 4 + 1) * WDIM + tid] = v.y;
            vrow[(q * 4 + 2) * WDIM + tid] = v.z;
            vrow[(q * 4 + 3) * WDIM + tid] = v.w;
        }
    }
    __syncthreads();

    const float4* wr = (const float4*)(lin_w + (size_t)e * 2 * WDIM);
    float uacc[4] = {0.f, 0.f, 0.f, 0.f};
    float tacc[4] = {0.f, 0.f, 0.f, 0.f};
#pragma unroll 8
    for (int q = 0; q < 32; ++q) {
        float4 w1 = wr[q];
        float4 w2 = wr[32 + q];
#pragma unroll
        for (int kk = 0; kk < 4; ++kk) {
            float4 v = *(const float4*)&vrow[(ks * 4 + kk) * WDIM + q * 4];
            uacc[kk] += w1.x * v.x + w1.y * v.y + w1.z * v.z + w1.w * v.w;
            tacc[kk] += w2.x * v.x + w2.y * v.y + w2.z * v.z + w2.w * v.w;
        }
    }
    const float lb = lin_b[e];
#pragma unroll
    for (int kk = 0; kk < 4; ++kk) {
        const int k = k0 + ks * 4 + kk;
        const size_t off = ((size_t)b * KDIM + k) * EDIM + e;
        u_ws[off] = uacc[kk];
        t_ws[off] = tacc[kk] + lb;
    }
}

// ---------------- k_e3: e[b,i,j] = sum a2|u+t| + 1.5(ru+rt) + bias ----------------
// grid 256: blk = b*64 + itile*2 + jh.  Block = 8 i's x 128 j's (one j-half).
// wave wv -> 32 j's; lane = (s = e-slice 0..7, jj = 0..7).
__global__ __launch_bounds__(256, 1) void k_e3(const float* __restrict__ a_vec,
                                               const float* __restrict__ bias,
                                               const float* __restrict__ u_ws,
                                               const float* __restrict__ t_ws,
                                               float* __restrict__ e_ws) {
    __shared__ float u_lds[8 * 288];   // [i 8][s 8 (stride 36)][32]
    __shared__ float a_lds[8 * 36];    // a2 = 0.4*a, slice-padded
    const int blk = blockIdx.x;
    const int b     = blk >> 6;
    const int itile = (blk >> 1) & 31;
    const int jh    = blk & 1;
    const int i0 = itile * 8;
    const int tid  = threadIdx.x;
    const int wv   = tid >> 6;
    const int lane = tid & 63;
    const int s  = lane >> 3;
    const int jj = lane & 7;
    const int e_base = s * 32;
    const int j0 = jh * 128 + wv * 32;

    // issue t loads first (32 float4/lane), overlap with staging
    const float* tb = t_ws + (size_t)b * KDIM * EDIM;
    float4 tld[4][8];
#pragma unroll
    for (int jg = 0; jg < 4; ++jg) {
        const float* tr = tb + (size_t)(j0 + jg * 8 + jj) * EDIM + e_base;
#pragma unroll
        for (int q = 0; q < 8; ++q) tld[jg][q] = *(const float4*)(tr + q * 4);
    }

    // stage u (8 rows) and a2 into padded LDS
    {
        const int r = tid >> 5;
        const int c = (tid & 31) * 8;
        const int ss = c >> 5, oo = c & 31;
        const float* up = u_ws + ((size_t)b * KDIM + i0 + r) * EDIM + c;
        *(float4*)&u_lds[r * 288 + ss * 36 + oo]     = *(const float4*)up;
        *(float4*)&u_lds[r * 288 + ss * 36 + oo + 4] = *(const float4*)(up + 4);
        if (tid < 64) {
            float4 av = *(const float4*)(a_vec + tid * 4);
            const int s2 = tid >> 3, o2 = (tid & 7) * 4;
            *(float4*)&a_lds[s2 * 36 + o2] =
                make_float4(0.4f * av.x, 0.4f * av.y, 0.4f * av.z, 0.4f * av.w);
        }
    }
    __syncthreads();

    float acc[8][4];
#pragma unroll
    for (int i = 0; i < 8; ++i)
#pragma unroll
        for (int jg = 0; jg < 4; ++jg) acc[i][jg] = 0.f;
    float ru[8] = {0.f,0.f,0.f,0.f,0.f,0.f,0.f,0.f};
    float rt[4] = {0.f,0.f,0.f,0.f};

#pragma unroll
    for (int q = 0; q < 8; ++q) {
        const float4 a2 = *(const float4*)&a_lds[s * 36 + q * 4];
#pragma unroll
        for (int jg = 0; jg < 4; ++jg) {
            const float4 t4 = tld[jg][q];
            rt[jg] += a2.x * t4.x + a2.y * t4.y + a2.z * t4.z + a2.w * t4.w;
        }
#pragma unroll
        for (int i = 0; i < 8; ++i) {
            const float4 u4 = *(const float4*)&u_lds[i * 288 + s * 36 + q * 4];
            ru[i] += a2.x * u4.x + a2.y * u4.y + a2.z * u4.z + a2.w * u4.w;
#pragma unroll
            for (int jg = 0; jg < 4; ++jg) {
                const float4 t4 = tld[jg][q];
                acc[i][jg] += a2.x * fabsf(u4.x + t4.x) + a2.y * fabsf(u4.y + t4.y)
                            + a2.z * fabsf(u4.z + t4.z) + a2.w * fabsf(u4.w + t4.w);
            }
        }
    }

    // reduce over s (lane bits 3..5)
#pragma unroll
    for (int i = 0; i < 8; ++i) {
        ru[i] += __shfl_xor(ru[i], 8, 64);
        ru[i] += __shfl_xor(ru[i], 16, 64);
        ru[i] += __shfl_xor(ru[i], 32, 64);
    }
#pragma unroll
    for (int jg = 0; jg < 4; ++jg) {
        rt[jg] += __shfl_xor(rt[jg], 8, 64);
        rt[jg] += __shfl_xor(rt[jg], 16, 64);
        rt[jg] += __shfl_xor(rt[jg], 32, 64);
    }
#pragma unroll
    for (int i = 0; i < 8; ++i)
#pragma unroll
        for (int jg = 0; jg < 4; ++jg) {
            float v = acc[i][jg];
            v += __shfl_xor(v, 8, 64);
            v += __shfl_xor(v, 16, 64);
            v += __shfl_xor(v, 32, 64);
            acc[i][jg] = v;
        }

    if (s == 0) {  // lanes 0..7, jj = lane
#pragma unroll
        for (int i = 0; i < 8; ++i)
#pragma unroll
            for (int jg = 0; jg < 4; ++jg) {
                const int j = j0 + jg * 8 + jj;
                const float v = acc[i][jg] + 1.5f * (ru[i] + rt[jg])
                              + bias[(size_t)(i0 + i) * KDIM + j];
                e_ws[((size_t)b * KDIM + i0 + i) * KDIM + j] = v;
            }
    }
}

// ---------------- k_sh3: softmax + h = sigmoid(attn @ v), transposed write ----------------
// grid 256: blk = b*64 + itile.  Block = 4 i's; wave wv: softmax row i0+wv, then w-quarter.
__global__ __launch_bounds__(256) void k_sh3(const float* __restrict__ x,
                                             const float* __restrict__ e_ws,
                                             float* __restrict__ out) {
    __shared__ float attn_lds[4 * 260];
    const int blk = blockIdx.x;
    const int b  = blk >> 6;
    const int i0 = (blk & 63) * 4;
    const int tid  = threadIdx.x;
    const int wv   = tid >> 6;
    const int lane = tid & 63;

    // softmax of row i0+wv
    {
        float4 ev = *(const float4*)(e_ws + ((size_t)b * KDIM + i0 + wv) * KDIM + lane * 4);
        float m = fmaxf(fmaxf(ev.x, ev.y), fmaxf(ev.z, ev.w));
#pragma unroll
        for (int o = 1; o < 64; o <<= 1) m = fmaxf(m, __shfl_xor(m, o, 64));
        float4 p;
        p.x = __expf(ev.x - m); p.y = __expf(ev.y - m);
        p.z = __expf(ev.z - m); p.w = __expf(ev.w - m);
        float ssum = p.x + p.y + p.z + p.w;
#pragma unroll
        for (int o = 1; o < 64; o <<= 1) ssum += __shfl_xor(ssum, o, 64);
        const float inv = 1.0f / ssum;
        p.x *= inv; p.y *= inv; p.z *= inv; p.w *= inv;
        *(float4*)&attn_lds[wv * 260 + lane * 4] = p;
    }
    __syncthreads();

    // h-phase: wave wv -> w in [wv*32, wv*32+32); lane = (w16 = lane>>2, js = lane&3)
    const int js  = lane & 3;
    const int w16 = lane >> 2;
    const float* xb = x + (size_t)b * WDIM * KDIM;
#pragma unroll
    for (int c = 0; c < 2; ++c) {
        const int w = wv * 32 + c * 16 + w16;
        const float* xr = xb + (size_t)w * KDIM;
        float acc[4] = {0.f, 0.f, 0.f, 0.f};
#pragma unroll
        for (int jl = 0; jl < 16; ++jl) {
            const float4 x4 = *(const float4*)(xr + jl * 16 + js * 4);
#pragma unroll
            for (int i = 0; i < 4; ++i) {
                const float4 a4 = *(const float4*)&attn_lds[i * 260 + jl * 16 + js * 4];
                acc[i] += a4.x * x4.x + a4.y * x4.y + a4.z * x4.z + a4.w * x4.w;
            }
        }
#pragma unroll
        for (int i = 0; i < 4; ++i) {
            acc[i] += __shfl_xor(acc[i], 1, 64);
            acc[i] += __shfl_xor(acc[i], 2, 64);
        }
        if (js == 0) {
            float4 o;
            o.x = 1.f / (1.f + __expf(-acc[0]));
            o.y = 1.f / (1.f + __expf(-acc[1]));
            o.z = 1.f / (1.f + __expf(-acc[2]));
            o.w = 1.f / (1.f + __expf(-acc[3]));
            *(float4*)(out + ((size_t)b * WDIM + w) * KDIM + i0) = o;
        }
    }
}

extern "C" void kernel_launch(void* const* d_in, const int* in_sizes, int n_in,
                              void* d_out, int out_size, void* d_ws, size_t ws_size,
                              hipStream_t stream) {
    (void)in_sizes; (void)n_in; (void)out_size; (void)ws_size;
    const float* x     = (const float*)d_in[0];
    const float* lin_w = (const float*)d_in[1];
    const float* lin_b = (const float*)d_in[2];
    const float* a_vec = (const float*)d_in[3];
    const float* bias  = (const float*)d_in[4];
    float* out = (float*)d_out;

    float* u_ws = (float*)d_ws;                      // 262144 f
    float* t_ws = u_ws + (size_t)NB * KDIM * EDIM;   // 262144 f
    float* e_ws = t_ws + (size_t)NB * KDIM * EDIM;   // 262144 f

    k_ut3<<<256, 256, 0, stream>>>(x, lin_w, lin_b, u_ws, t_ws);
    k_e3<<<256, 256, 0, stream>>>(a_vec, bias, u_ws, t_ws, e_ws);
    k_sh3<<<256, 256, 0, stream>>>(x, e_ws, out);
}